// Round 13
// baseline (76.738 us; speedup 1.0000x reference)
//
#include <hip/hip_runtime.h>
#include <hip/hip_bf16.h>

#define B_ 4
#define S_ 4096
#define D_ 1024
#define H_ 128

typedef _Float16 half8 __attribute__((ext_vector_type(8)));
typedef _Float16 half4v __attribute__((ext_vector_type(4)));
typedef float float4v __attribute__((ext_vector_type(4)));

// Fragment-major layouts (hot-kernel loads are base + lane*16B 1KB bursts):
//   WTz[((w*32 + K32)*8 + nt)*512 + lane*8 + e] = W_w[K32*32 + (lane>>4)*8 + e][nt*16 + (lane&15)]
//   Kz[(b*128+tt)*4096 + (k2*2+c)*512 + lane*8 + e]
//     = K[b][tt*32 + permbase(lane&15) + 4c][k2*32 + (lane>>4)*8 + e]
//   Vz[(b*128+tt)*4096 + hc*512 + lane*8 + e]
//     = V[b][tt*32 + (lane>>4)*8 + e][hc*16 + (lane&15)]
// (permbase(l) = ((l>>2)<<3)+(l&3))
// R11 lesson: fragment reads from row-major global scatter across 16 rows ->
// TA-serialized.  R12 lesson: __syncthreads in the K-loop forces vmcnt(0)
// drains (4 structures all stuck ~40us).  R13: wave-private LDS staging ->
// NO barriers in the loop at all.

// ------------- kernel 1: W[k][n] fp32 -> WTz fragment-major f16 -------------
__global__ __launch_bounds__(256) void k_cvt_w(const float* __restrict__ Wq,
                                               const float* __restrict__ Wk,
                                               const float* __restrict__ Wv,
                                               _Float16* __restrict__ WTz) {
    const float* W = blockIdx.y == 0 ? Wq : (blockIdx.y == 1 ? Wk : Wv);
    const int idx  = blockIdx.x * 256 + threadIdx.x;   // 0..16383 (grid.x = 64)
    const int lane = idx & 63, nt = (idx >> 6) & 7, K32 = idx >> 9;
    const int lo = lane & 15, hi = lane >> 4;
    half8 v;
#pragma unroll
    for (int e = 0; e < 8; ++e)
        v[e] = (_Float16)W[(K32 * 32 + hi * 8 + e) * H_ + nt * 16 + lo];
    *(half8*)(WTz + (size_t)(((int)blockIdx.y * 32 + K32) * 8 + nt) * 512 + lane * 8) = v;
}

// ------------- kernel 2: QKV projection GEMM (R13: barrier-free) -----------
// 768 blocks (M-tile 64; {m, m+256, m+512} same XCD -> X L2/L1-shared).
// 4 waves; wave wid owns rows [m0+wid*16, +16) x all 128 cols, staged in a
// WAVE-PRIVATE LDS tile [16][136] -> zero __syncthreads in the K-loop ->
// no forced vmcnt(0) drains; X prefetched one 128-K-tile ahead in regs.
// B operand read directly from WTz as 1KB bursts (no LDS).  Epilogue: acc ->
// Ct[64][136] (aliases staging, own-region writes), one barrier, burst stores.
__global__ __launch_bounds__(256, 3) void k_proj(const float* __restrict__ X,
                                                 const _Float16* __restrict__ WTz,
                                                 const float* __restrict__ bq,
                                                 const float* __restrict__ bk,
                                                 const float* __restrict__ bv,
                                                 _Float16* __restrict__ Qf,
                                                 _Float16* __restrict__ Kz,
                                                 _Float16* __restrict__ Vz) {
    __shared__ _Float16 smem[64 * 136];   // 4 x wave-private [16][136]; Ct alias

    const int t    = threadIdx.x;
    const int bid  = blockIdx.x;
    const int w    = bid >> 8;                     // 0=q 1=k 2=v
    const int m0   = (bid & 255) * 64;
    const int lane = t & 63, wid = t >> 6;
    const int lo   = lane & 15, hi = lane >> 4;

    _Float16* Aw = smem + wid * (16 * 136);        // wave-private tile
    const float* Xw = X + (size_t)(m0 + wid * 16) * D_;
    const _Float16* Wz = WTz + (size_t)(w * 32 * 8) * 512 + lane * 8;

    const int sr = lane >> 5, sc = (lane & 31) * 4;   // staging: row i2*2+sr, 4 f32

    // prologue: K-tile 0 into regs
    float4v xreg[8];
#pragma unroll
    for (int i2 = 0; i2 < 8; ++i2)
        xreg[i2] = *(const float4v*)(Xw + (size_t)(i2 * 2 + sr) * D_ + sc);

    float4v acc[8];
#pragma unroll
    for (int nt = 0; nt < 8; ++nt) acc[nt] = {0.f, 0.f, 0.f, 0.f};

    for (int it = 0; it < 8; ++it) {
        // ---- regs -> wave-private LDS (cvt fp32->f16); no barrier ----
#pragma unroll
        for (int i2 = 0; i2 < 8; ++i2) {
            float4v xv = xreg[i2];
            half4v hv;
            hv[0] = (_Float16)xv[0]; hv[1] = (_Float16)xv[1];
            hv[2] = (_Float16)xv[2]; hv[3] = (_Float16)xv[3];
            *(half4v*)(&Aw[(i2 * 2 + sr) * 136 + sc]) = hv;
        }
        // ---- prefetch next K-tile (overlaps compute; no drain point) ----
        if (it < 7) {
            const int k0n = (it + 1) * 128;
#pragma unroll
            for (int i2 = 0; i2 < 8; ++i2)
                xreg[i2] = *(const float4v*)(Xw + (size_t)(i2 * 2 + sr) * D_ + k0n + sc);
        }
        // ---- compute 4 K32 sub-steps: af from own LDS, bf as WTz bursts ----
#pragma unroll
        for (int k32 = 0; k32 < 4; ++k32) {
            const int K32 = it * 4 + k32;
            half8 af = *(const half8*)(&Aw[lo * 136 + k32 * 32 + hi * 8]);
            const _Float16* bp = Wz + (size_t)(K32 * 8) * 512;
#pragma unroll
            for (int nt = 0; nt < 8; ++nt) {
                half8 bf = *(const half8*)(bp + (size_t)nt * 512);
                acc[nt] = __builtin_amdgcn_mfma_f32_16x16x32_f16(af, bf, acc[nt], 0, 0, 0);
            }
        }
    }

    // ---- epilogue: acc (+bias,*scale) -> Ct rows wid*16..+15 (own region) ----
    const float* bias = (w == 0) ? bq : ((w == 1) ? bk : bv);
    const float scale = (w == 0) ? (0.08838834764831845f * 1.4426950408889634f) : 1.0f;
    _Float16* Ct = smem;                           // [64][136]
#pragma unroll
    for (int nt = 0; nt < 8; ++nt) {
        const int col  = nt * 16 + lo;
        const float bn = bias[col];
#pragma unroll
        for (int j = 0; j < 4; ++j)
            Ct[(wid * 16 + 4 * hi + j) * 136 + col] =
                (_Float16)((acc[nt][j] + bn) * scale);
    }
    __syncthreads();                               // cross-wave store phase

    const int bb  = m0 >> 12;                      // batch
    const int tt0 = (m0 & (S_ - 1)) >> 5;          // first 32-row KV tile

    if (w == 0) {                                  // Q: row-major bursts
        const int r = t >> 2, c0 = (t & 3) * 32;
        _Float16* dst = Qf + (size_t)(m0 + r) * H_ + c0;
        const _Float16* srcp = &Ct[r * 136 + c0];
#pragma unroll
        for (int cc = 0; cc < 4; ++cc)
            *(half8*)(dst + cc * 8) = *(const half8*)(srcp + cc * 8);
    } else if (w == 1) {                           // K: fragment-major bursts
        const int rowp = ((lo >> 2) << 3) + (lo & 3);
#pragma unroll
        for (int q = 0; q < 4; ++q) {
            const int fid = wid * 4 + q;           // 16 frags: 2 tiles x 4 k2 x 2 c
            const int ft = fid >> 3, k2 = (fid >> 1) & 3, c = fid & 1;
            const int row = ft * 32 + rowp + 4 * c;
            half8 v = *(const half8*)(&Ct[row * 136 + k2 * 32 + hi * 8]);
            *(half8*)(Kz + (size_t)(bb * 128 + tt0 + ft) * 4096 +
                      (k2 * 2 + c) * 512 + lane * 8) = v;
        }
    } else {                                       // V: transposed fragment-major
#pragma unroll
        for (int q = 0; q < 4; ++q) {
            const int fid = wid * 4 + q;           // 16 frags: 2 tiles x 8 hc
            const int ft = fid >> 3, hc = fid & 7;
            half8 v;
#pragma unroll
            for (int e = 0; e < 8; ++e)
                v[e] = Ct[(ft * 32 + hi * 8 + e) * 136 + hc * 16 + lo];
            *(half8*)(Vz + (size_t)(bb * 128 + tt0 + ft) * 4096 +
                      hc * 512 + lane * 8) = v;
        }
    }
}

// ---------------- kernel 3: causal flash attention (UNCHANGED from R8) ----
__global__ __launch_bounds__(512, 2) void k_attn(const _Float16* __restrict__ Qf,
                                                 const _Float16* __restrict__ Kz,
                                                 const _Float16* __restrict__ Vz,
                                                 float* __restrict__ Out) {
    __shared__ float    sm_l[8][32];
    __shared__ _Float16 sm_o[8][32][136];   // [wave][q][h], pad 128->136

    const int t    = threadIdx.x;
    const int lane = t & 63, wid = t >> 6;
    const int lo = lane & 15, hi = lane >> 4;

    const int i   = blockIdx.x;            // 0..511
    const int b   = (i >> 1) & 3;          // batch -> XCD pair {2b, 2b+1}
    const int qtr = ((i >> 3) << 1) | (i & 1);          // 0..127
    const int qt  = (qtr < 64) ? qtr : (191 - qtr);     // zigzag: i & i+256 complement
    const int q0  = qt << 5;               // 32 queries: q0..q0+31

    const _Float16* Qb = Qf + (size_t)b * (S_ * H_);
    const _Float16* Kb = Kz + (size_t)b * 524288;   // 128 tiles * 4096
    const _Float16* Vb = Vz + (size_t)b * 524288;

    half8 qfa[4], qfb[4];
#pragma unroll
    for (int kk = 0; kk < 4; ++kk) {
        qfa[kk] = *(const half8*)(Qb + (size_t)(q0 + lo) * H_ + kk * 32 + hi * 8);
        qfb[kk] = *(const half8*)(Qb + (size_t)(q0 + 16 + lo) * H_ + kk * 32 + hi * 8);
    }

    float4v oa[8], ob[8];
#pragma unroll
    for (int hc = 0; hc < 8; ++hc) { oa[hc] = {0.f,0.f,0.f,0.f}; ob[hc] = {0.f,0.f,0.f,0.f}; }
    float la = 0.f, lb = 0.f;   // LANE-LOCAL partial row-sums (reduced after loop)

    const int lane8 = lane * 8;
    const int ntiles = qt + 1;             // keys 0..q0+31, 32/tile

    // prime the K double-buffer with this wave's first tile
    half8 kc0[4], kc1[4];
    if (wid < ntiles) {
        const _Float16* Kt = Kb + (size_t)wid * 4096 + lane8;
#pragma unroll
        for (int kk = 0; kk < 4; ++kk) {
            kc0[kk] = *(const half8*)(Kt + (kk * 2    ) * 512);
            kc1[kk] = *(const half8*)(Kt + (kk * 2 + 1) * 512);
        }
    }

    for (int tt = wid; tt < ntiles; tt += 8) {
        // ---- V loads issued first: latency hides under QK + exp ----
        const _Float16* Vt = Vb + (size_t)tt * 4096 + lane8;
        half8 vf[8];
#pragma unroll
        for (int hc = 0; hc < 8; ++hc)
            vf[hc] = *(const half8*)(Vt + hc * 512);
        // ---- prefetch next K tile (clamped re-load of current on last iter) ----
        const int tn = (tt + 8 < ntiles) ? (tt + 8) : tt;
        half8 kn0[4], kn1[4];
        {
            const _Float16* Ktn = Kb + (size_t)tn * 4096 + lane8;
#pragma unroll
            for (int kk = 0; kk < 4; ++kk) {
                kn0[kk] = *(const half8*)(Ktn + (kk * 2    ) * 512);
                kn1[kk] = *(const half8*)(Ktn + (kk * 2 + 1) * 512);
            }
        }
        // ---- QK^T on the current (already-resident) K fragments ----
        float4v s0a = {0.f,0.f,0.f,0.f}, s1a = {0.f,0.f,0.f,0.f};
        float4v s0b = {0.f,0.f,0.f,0.f}, s1b = {0.f,0.f,0.f,0.f};
#pragma unroll
        for (int kk = 0; kk < 4; ++kk) {
            s0a = __builtin_amdgcn_mfma_f32_16x16x32_f16(kc0[kk], qfa[kk], s0a, 0, 0, 0);
            s0b = __builtin_amdgcn_mfma_f32_16x16x32_f16(kc0[kk], qfb[kk], s0b, 0, 0, 0);
            s1a = __builtin_amdgcn_mfma_f32_16x16x32_f16(kc1[kk], qfa[kk], s1a, 0, 0, 0);
            s1b = __builtin_amdgcn_mfma_f32_16x16x32_f16(kc1[kk], qfb[kk], s1b, 0, 0, 0);
        }
        // s0x[j] = S[q][k0+8hi+j], s1x[j] = S[q][k0+8hi+4+j]
        if (tt == qt) {   // diagonal tile: only place masking is needed
#pragma unroll
            for (int j = 0; j < 4; ++j) {
                const int c0 = 8 * hi + j, c1 = 8 * hi + 4 + j;
                if (c0 > lo)      s0a[j] = -INFINITY;
                if (c1 > lo)      s1a[j] = -INFINITY;
                if (c0 > 16 + lo) s0b[j] = -INFINITY;
                if (c1 > 16 + lo) s1b[j] = -INFINITY;
            }
        }
        // ---- no-max softmax, exp2 direct (exp2(-inf) = 0 handles masks) ----
        float pa0 = __builtin_amdgcn_exp2f(s0a[0]), pa1 = __builtin_amdgcn_exp2f(s0a[1]);
        float pa2 = __builtin_amdgcn_exp2f(s0a[2]), pa3 = __builtin_amdgcn_exp2f(s0a[3]);
        float pa4 = __builtin_amdgcn_exp2f(s1a[0]), pa5 = __builtin_amdgcn_exp2f(s1a[1]);
        float pa6 = __builtin_amdgcn_exp2f(s1a[2]), pa7 = __builtin_amdgcn_exp2f(s1a[3]);
        float pb0 = __builtin_amdgcn_exp2f(s0b[0]), pb1 = __builtin_amdgcn_exp2f(s0b[1]);
        float pb2 = __builtin_amdgcn_exp2f(s0b[2]), pb3 = __builtin_amdgcn_exp2f(s0b[3]);
        float pb4 = __builtin_amdgcn_exp2f(s1b[0]), pb5 = __builtin_amdgcn_exp2f(s1b[1]);
        float pb6 = __builtin_amdgcn_exp2f(s1b[2]), pb7 = __builtin_amdgcn_exp2f(s1b[3]);
        la += ((pa0+pa1)+(pa2+pa3)) + ((pa4+pa5)+(pa6+pa7));   // lane-local only
        lb += ((pb0+pb1)+(pb2+pb3)) + ((pb4+pb5)+(pb6+pb7));
        half8 pfa, pfb;
        pfa[0]=(_Float16)pa0; pfa[1]=(_Float16)pa1; pfa[2]=(_Float16)pa2; pfa[3]=(_Float16)pa3;
        pfa[4]=(_Float16)pa4; pfa[5]=(_Float16)pa5; pfa[6]=(_Float16)pa6; pfa[7]=(_Float16)pa7;
        pfb[0]=(_Float16)pb0; pfb[1]=(_Float16)pb1; pfb[2]=(_Float16)pb2; pfb[3]=(_Float16)pb3;
        pfb[4]=(_Float16)pb4; pfb[5]=(_Float16)pb5; pfb[6]=(_Float16)pb6; pfb[7]=(_Float16)pb7;
        // ---- PV: V fragments shared between both sub-tiles; no rescale ----
#pragma unroll
        for (int hc = 0; hc < 8; ++hc) {
            oa[hc] = __builtin_amdgcn_mfma_f32_16x16x32_f16(vf[hc], pfa, oa[hc], 0, 0, 0);
            ob[hc] = __builtin_amdgcn_mfma_f32_16x16x32_f16(vf[hc], pfb, ob[hc], 0, 0, 0);
        }
        // ---- rotate K buffers ----
#pragma unroll
        for (int kk = 0; kk < 4; ++kk) { kc0[kk] = kn0[kk]; kc1[kk] = kn1[kk]; }
    }

    // ---- single deferred l-reduction ----
    la += __shfl_xor(la, 16); la += __shfl_xor(la, 32);
    lb += __shfl_xor(lb, 16); lb += __shfl_xor(lb, 32);

    // ---- merge the 8 KV-split partials (straight sums) ----
    sm_l[wid][lo]      = la;
    sm_l[wid][16 + lo] = lb;
#pragma unroll
    for (int hc = 0; hc < 8; ++hc) {
        half4v va, vb;
#pragma unroll
        for (int j = 0; j < 4; ++j) { va[j] = (_Float16)oa[hc][j]; vb[j] = (_Float16)ob[hc][j]; }
        *(half4v*)(&sm_o[wid][lo][hc * 16 + 4 * hi])      = va;
        *(half4v*)(&sm_o[wid][16 + lo][hc * 16 + 4 * hi]) = vb;
    }
    __syncthreads();

#pragma unroll
    for (int qh = 0; qh < 2; ++qh) {
        const int q = qh * 16 + lo;
        float L = 0.f;
#pragma unroll
        for (int w = 0; w < 8; ++w) L += sm_l[w][q];
        const float invL = 1.f / L;
        float4v ov = {0.f, 0.f, 0.f, 0.f};
#pragma unroll
        for (int w = 0; w < 8; ++w) {
            half4v tv = *(const half4v*)(&sm_o[w][q][wid * 16 + 4 * hi]);
#pragma unroll
            for (int j = 0; j < 4; ++j) ov[j] += (float)tv[j];
        }
#pragma unroll
        for (int j = 0; j < 4; ++j) ov[j] *= invL;
        *(float4v*)(Out + ((size_t)b * S_ + q0 + q) * H_ + wid * 16 + 4 * hi) = ov;
    }
}

extern "C" void kernel_launch(void* const* d_in, const int* in_sizes, int n_in,
                              void* d_out, int out_size, void* d_ws, size_t ws_size,
                              hipStream_t stream) {
    const float* x  = (const float*)d_in[0];
    const float* Wq = (const float*)d_in[1];
    const float* bq = (const float*)d_in[2];
    const float* Wk = (const float*)d_in[3];
    const float* bk = (const float*)d_in[4];
    const float* Wv = (const float*)d_in[5];
    const float* bv = (const float*)d_in[6];
    float* out = (float*)d_out;   // reference output dtype = float32

    char* ws = (char*)d_ws;
    _Float16* WTz = (_Float16*)ws;                       //   786,432 B fragment-major
    _Float16* Qf  = (_Float16*)(ws + 786432);            // 4,194,304 B
    _Float16* Kz  = (_Float16*)(ws + 786432 + 4194304);  // 4 MB fragment-major
    _Float16* Vz  = (_Float16*)(ws + 786432 + 8388608);  // 4 MB fragment-major

    hipLaunchKernelGGL(k_cvt_w, dim3(64, 3), dim3(256), 0, stream, Wq, Wk, Wv, WTz);
    hipLaunchKernelGGL(k_proj, dim3(768), dim3(256), 0, stream,
                       x, WTz, bq, bk, bv, Qf, Kz, Vz);
    hipLaunchKernelGGL(k_attn, dim3(512), dim3(512), 0, stream, Qf, Kz, Vz, out);
}

// Round 14
// 60.442 us; speedup vs baseline: 1.2696x; 1.2696x over previous
//
#include <hip/hip_runtime.h>
#include <hip/hip_bf16.h>

#define B_ 4
#define S_ 4096
#define D_ 1024
#define H_ 128

typedef _Float16 half8 __attribute__((ext_vector_type(8)));
typedef _Float16 half4v __attribute__((ext_vector_type(4)));
typedef float float4v __attribute__((ext_vector_type(4)));

// K/V fragment-major layouts (per batch: 128 tiles x 8 frags x 64 lanes x 8 f16):
//   Kz[(b*128+tt)*4096 + (k2*2+c)*512 + lane*8 + e]
//     = K[b][tt*32 + permbase(lane&15) + 4c][k2*32 + (lane>>4)*8 + e]
//   Vz[(b*128+tt)*4096 + hc*512 + lane*8 + e]
//     = V[b][tt*32 + (lane>>4)*8 + e][hc*16 + (lane&15)]
// (permbase(l) = ((l>>2)<<3)+(l&3))
// Session lessons: R8: fragment loads must be base+lane*16B bursts.  R11:
// fragment reads from row-major global scatter 16 rows -> TA-serialized.
// R13: reg-staged prefetch gets SUNK by the register allocator (VGPR=52) ->
// use global_load_lds (async, no VGPRs, can't be sunk) = the m97 structure.

__device__ __forceinline__ void gload_lds16(const void* g, void* l) {
    __builtin_amdgcn_global_load_lds(
        (const __attribute__((address_space(1))) unsigned int*)g,
        (__attribute__((address_space(3))) unsigned int*)l, 16, 0, 0);
}

// ---------------- kernel 1: W[k][n] fp32 -> WT[w][n][k] f16 ----------------
__global__ __launch_bounds__(256) void k_cvt_w(const float* __restrict__ Wq,
                                               const float* __restrict__ Wk,
                                               const float* __restrict__ Wv,
                                               _Float16* __restrict__ WT) {
    const float* W = blockIdx.y == 0 ? Wq : (blockIdx.y == 1 ? Wk : Wv);
    int idx = blockIdx.x * 256 + threadIdx.x;   // 0..131071  (grid.x = 512)
    int k = idx >> 7, n = idx & 127;
    WT[(size_t)blockIdx.y * (H_ * D_) + (size_t)n * D_ + k] = (_Float16)W[idx];
}

// ------------- kernel 2: QKV projection GEMM (R14: m97 structure) ----------
// 768 blocks (M-tile 64; {m, m+256, m+512} same XCD -> X L2-shared).  BK=64,
// 16 K-steps, single-buffered, 2 barriers/step; staging via global_load_lds
// width=16 (async direct-to-LDS: no VGPR round trip, allocator can't sink it;
// 3 blocks/CU overlap each other's barrier drains, m114/m97 mechanism).
// LDS dest is linear (wave-uniform base + lane*16B), so bank-swizzle is done
// by PRE-SWIZZLING THE GLOBAL SOURCE col: phys c' holds logical c'^v, where
// v = (row&7)*4 [A, f32 units] / (row&7)*8 [B, f16 units]; reads apply the
// same XOR (involution).  A is fp32 in LDS; af = 2x float4 read + cvt.
__global__ __launch_bounds__(256, 3) void k_proj(const float* __restrict__ X,
                                                 const _Float16* __restrict__ WT,
                                                 const float* __restrict__ bq,
                                                 const float* __restrict__ bk,
                                                 const float* __restrict__ bv,
                                                 _Float16* __restrict__ Qf,
                                                 _Float16* __restrict__ Kz,
                                                 _Float16* __restrict__ Vz) {
    __shared__ char smem[32768];        // As f32[64][64] 16KB | Bs f16[128][64] 16KB
    char* AsB = smem;
    char* BsB = smem + 16384;

    const int t    = threadIdx.x;
    const int bid  = blockIdx.x;
    const int w    = bid >> 8;                     // 0=q 1=k 2=v
    const int m0   = (bid & 255) * 64;
    const int lane = t & 63, wid = t >> 6;
    const int lo   = lane & 15, hi = lane >> 4;
    const int wr   = wid >> 1, wc = wid & 1;

    const _Float16* Wt = WT + (size_t)w * (H_ * D_);

    // staging geometry (per wave, per issue j: one contiguous 1KB LDS unit)
    const int raj = wid * 16 + (lane >> 4);        // + j*4   (A rows, 4/issue)
    const int rbj = wid * 32 + (lane >> 3);        // + j*8   (B rows, 8/issue)
    const int ca0 = (lane & 15) * 4;               // A logical 16B chunk (f32 col)
    const int cb0 = (lane & 7) * 8;                // B logical 16B chunk (f16 col)

    float4v acc[2][4];
#pragma unroll
    for (int mt = 0; mt < 2; ++mt)
#pragma unroll
        for (int nt = 0; nt < 4; ++nt) acc[mt][nt] = {0.f, 0.f, 0.f, 0.f};

    for (int it = 0; it < 16; ++it) {
        const int k0 = it * 64;
        // ---- async stage A (fp32) + B (f16), source-swizzled ----
#pragma unroll
        for (int j = 0; j < 4; ++j) {
            const int ra = raj + j * 4;
            const int ca = ca0 ^ ((ra & 7) * 4);
            gload_lds16(X + (size_t)(m0 + ra) * D_ + k0 + ca,
                        AsB + (wid * 16 + j * 4) * 256);
            const int rb = rbj + j * 8;
            const int cb = cb0 ^ ((rb & 7) * 8);
            gload_lds16(Wt + (size_t)rb * D_ + k0 + cb,
                        BsB + (wid * 32 + j * 8) * 128);
        }
        __syncthreads();   // staging complete (vmcnt drain) + visible
        // ---- MFMA phase ----
#pragma unroll
        for (int kk = 0; kk < 2; ++kk) {
            const int cb = kk * 32 + hi * 8;
            half8 af[2];
#pragma unroll
            for (int mt = 0; mt < 2; ++mt) {
                const int r = wr * 32 + mt * 16 + lo;
                const int v = (r & 7) * 4;
                float4v a0 = *(const float4v*)(AsB + r * 256 + ((cb ^ v) << 2));
                float4v a1 = *(const float4v*)(AsB + r * 256 + (((cb + 4) ^ v) << 2));
                half8 h;
                h[0]=(_Float16)a0[0]; h[1]=(_Float16)a0[1]; h[2]=(_Float16)a0[2]; h[3]=(_Float16)a0[3];
                h[4]=(_Float16)a1[0]; h[5]=(_Float16)a1[1]; h[6]=(_Float16)a1[2]; h[7]=(_Float16)a1[3];
                af[mt] = h;
            }
            half8 bf[4];
#pragma unroll
            for (int nt = 0; nt < 4; ++nt) {
                const int rb2 = wc * 64 + nt * 16 + lo;
                const int vb  = (rb2 & 7) * 8;
                bf[nt] = *(const half8*)(BsB + rb2 * 128 + (((cb) ^ vb) << 1));
            }
#pragma unroll
            for (int mt = 0; mt < 2; ++mt)
#pragma unroll
                for (int nt = 0; nt < 4; ++nt)
                    acc[mt][nt] = __builtin_amdgcn_mfma_f32_16x16x32_f16(
                        af[mt], bf[nt], acc[mt][nt], 0, 0, 0);
        }
        __syncthreads();   // LDS consumed; safe to restage
    }

    // ---- epilogue: acc (+bias, *scale) -> Ct[64][136] -> burst stores ----
    const float* bias = (w == 0) ? bq : ((w == 1) ? bk : bv);
    const float scale = (w == 0) ? (0.08838834764831845f * 1.4426950408889634f) : 1.0f;
    _Float16* Ct = (_Float16*)smem;                // [64][136] = 17408 B, fits
#pragma unroll
    for (int mt = 0; mt < 2; ++mt)
#pragma unroll
        for (int nt = 0; nt < 4; ++nt) {
            const int col   = wc * 64 + nt * 16 + lo;
            const float bn  = bias[col];
            const int rbase = wr * 32 + mt * 16 + 4 * hi;
#pragma unroll
            for (int j = 0; j < 4; ++j)
                Ct[(rbase + j) * 136 + col] = (_Float16)((acc[mt][nt][j] + bn) * scale);
        }
    __syncthreads();

    const int bb  = m0 >> 12;                      // batch
    const int tt0 = (m0 & (S_ - 1)) >> 5;          // first 32-row KV tile

    if (w == 0) {                                  // Q: row-major bursts
        const int r = t >> 2, c0 = (t & 3) * 32;
        _Float16* dst = Qf + (size_t)(m0 + r) * H_ + c0;
        const _Float16* srcp = &Ct[r * 136 + c0];
#pragma unroll
        for (int cc = 0; cc < 4; ++cc)
            *(half8*)(dst + cc * 8) = *(const half8*)(srcp + cc * 8);
    } else if (w == 1) {                           // K: fragment-major bursts
        const int rowp = ((lo >> 2) << 3) + (lo & 3);
#pragma unroll
        for (int q = 0; q < 4; ++q) {
            const int fid = wid * 4 + q;           // 16 frags: 2 tiles x 4 k2 x 2 c
            const int ft = fid >> 3, k2 = (fid >> 1) & 3, c = fid & 1;
            const int row = ft * 32 + rowp + 4 * c;
            half8 v = *(const half8*)(&Ct[row * 136 + k2 * 32 + hi * 8]);
            *(half8*)(Kz + (size_t)(bb * 128 + tt0 + ft) * 4096 +
                      (k2 * 2 + c) * 512 + lane * 8) = v;
        }
    } else {                                       // V: transposed fragment-major
#pragma unroll
        for (int q = 0; q < 4; ++q) {
            const int fid = wid * 4 + q;           // 16 frags: 2 tiles x 8 hc
            const int ft = fid >> 3, hc = fid & 7;
            half8 v;
#pragma unroll
            for (int e = 0; e < 8; ++e)
                v[e] = Ct[(ft * 32 + hi * 8 + e) * 136 + hc * 16 + lo];
            *(half8*)(Vz + (size_t)(bb * 128 + tt0 + ft) * 4096 +
                      hc * 512 + lane * 8) = v;
        }
    }
}

// ---------------- kernel 3: causal flash attention (UNCHANGED from R8) ----
__global__ __launch_bounds__(512, 2) void k_attn(const _Float16* __restrict__ Qf,
                                                 const _Float16* __restrict__ Kz,
                                                 const _Float16* __restrict__ Vz,
                                                 float* __restrict__ Out) {
    __shared__ float    sm_l[8][32];
    __shared__ _Float16 sm_o[8][32][136];   // [wave][q][h], pad 128->136

    const int t    = threadIdx.x;
    const int lane = t & 63, wid = t >> 6;
    const int lo = lane & 15, hi = lane >> 4;

    const int i   = blockIdx.x;            // 0..511
    const int b   = (i >> 1) & 3;          // batch -> XCD pair {2b, 2b+1}
    const int qtr = ((i >> 3) << 1) | (i & 1);          // 0..127
    const int qt  = (qtr < 64) ? qtr : (191 - qtr);     // zigzag: i & i+256 complement
    const int q0  = qt << 5;               // 32 queries: q0..q0+31

    const _Float16* Qb = Qf + (size_t)b * (S_ * H_);
    const _Float16* Kb = Kz + (size_t)b * 524288;   // 128 tiles * 4096
    const _Float16* Vb = Vz + (size_t)b * 524288;

    half8 qfa[4], qfb[4];
#pragma unroll
    for (int kk = 0; kk < 4; ++kk) {
        qfa[kk] = *(const half8*)(Qb + (size_t)(q0 + lo) * H_ + kk * 32 + hi * 8);
        qfb[kk] = *(const half8*)(Qb + (size_t)(q0 + 16 + lo) * H_ + kk * 32 + hi * 8);
    }

    float4v oa[8], ob[8];
#pragma unroll
    for (int hc = 0; hc < 8; ++hc) { oa[hc] = {0.f,0.f,0.f,0.f}; ob[hc] = {0.f,0.f,0.f,0.f}; }
    float la = 0.f, lb = 0.f;   // LANE-LOCAL partial row-sums (reduced after loop)

    const int lane8 = lane * 8;
    const int ntiles = qt + 1;             // keys 0..q0+31, 32/tile

    // prime the K double-buffer with this wave's first tile
    half8 kc0[4], kc1[4];
    if (wid < ntiles) {
        const _Float16* Kt = Kb + (size_t)wid * 4096 + lane8;
#pragma unroll
        for (int kk = 0; kk < 4; ++kk) {
            kc0[kk] = *(const half8*)(Kt + (kk * 2    ) * 512);
            kc1[kk] = *(const half8*)(Kt + (kk * 2 + 1) * 512);
        }
    }

    for (int tt = wid; tt < ntiles; tt += 8) {
        // ---- V loads issued first: latency hides under QK + exp ----
        const _Float16* Vt = Vb + (size_t)tt * 4096 + lane8;
        half8 vf[8];
#pragma unroll
        for (int hc = 0; hc < 8; ++hc)
            vf[hc] = *(const half8*)(Vt + hc * 512);
        // ---- prefetch next K tile (clamped re-load of current on last iter) ----
        const int tn = (tt + 8 < ntiles) ? (tt + 8) : tt;
        half8 kn0[4], kn1[4];
        {
            const _Float16* Ktn = Kb + (size_t)tn * 4096 + lane8;
#pragma unroll
            for (int kk = 0; kk < 4; ++kk) {
                kn0[kk] = *(const half8*)(Ktn + (kk * 2    ) * 512);
                kn1[kk] = *(const half8*)(Ktn + (kk * 2 + 1) * 512);
            }
        }
        // ---- QK^T on the current (already-resident) K fragments ----
        float4v s0a = {0.f,0.f,0.f,0.f}, s1a = {0.f,0.f,0.f,0.f};
        float4v s0b = {0.f,0.f,0.f,0.f}, s1b = {0.f,0.f,0.f,0.f};
#pragma unroll
        for (int kk = 0; kk < 4; ++kk) {
            s0a = __builtin_amdgcn_mfma_f32_16x16x32_f16(kc0[kk], qfa[kk], s0a, 0, 0, 0);
            s0b = __builtin_amdgcn_mfma_f32_16x16x32_f16(kc0[kk], qfb[kk], s0b, 0, 0, 0);
            s1a = __builtin_amdgcn_mfma_f32_16x16x32_f16(kc1[kk], qfa[kk], s1a, 0, 0, 0);
            s1b = __builtin_amdgcn_mfma_f32_16x16x32_f16(kc1[kk], qfb[kk], s1b, 0, 0, 0);
        }
        // s0x[j] = S[q][k0+8hi+j], s1x[j] = S[q][k0+8hi+4+j]
        if (tt == qt) {   // diagonal tile: only place masking is needed
#pragma unroll
            for (int j = 0; j < 4; ++j) {
                const int c0 = 8 * hi + j, c1 = 8 * hi + 4 + j;
                if (c0 > lo)      s0a[j] = -INFINITY;
                if (c1 > lo)      s1a[j] = -INFINITY;
                if (c0 > 16 + lo) s0b[j] = -INFINITY;
                if (c1 > 16 + lo) s1b[j] = -INFINITY;
            }
        }
        // ---- no-max softmax, exp2 direct (exp2(-inf) = 0 handles masks) ----
        float pa0 = __builtin_amdgcn_exp2f(s0a[0]), pa1 = __builtin_amdgcn_exp2f(s0a[1]);
        float pa2 = __builtin_amdgcn_exp2f(s0a[2]), pa3 = __builtin_amdgcn_exp2f(s0a[3]);
        float pa4 = __builtin_amdgcn_exp2f(s1a[0]), pa5 = __builtin_amdgcn_exp2f(s1a[1]);
        float pa6 = __builtin_amdgcn_exp2f(s1a[2]), pa7 = __builtin_amdgcn_exp2f(s1a[3]);
        float pb0 = __builtin_amdgcn_exp2f(s0b[0]), pb1 = __builtin_amdgcn_exp2f(s0b[1]);
        float pb2 = __builtin_amdgcn_exp2f(s0b[2]), pb3 = __builtin_amdgcn_exp2f(s0b[3]);
        float pb4 = __builtin_amdgcn_exp2f(s1b[0]), pb5 = __builtin_amdgcn_exp2f(s1b[1]);
        float pb6 = __builtin_amdgcn_exp2f(s1b[2]), pb7 = __builtin_amdgcn_exp2f(s1b[3]);
        la += ((pa0+pa1)+(pa2+pa3)) + ((pa4+pa5)+(pa6+pa7));   // lane-local only
        lb += ((pb0+pb1)+(pb2+pb3)) + ((pb4+pb5)+(pb6+pb7));
        half8 pfa, pfb;
        pfa[0]=(_Float16)pa0; pfa[1]=(_Float16)pa1; pfa[2]=(_Float16)pa2; pfa[3]=(_Float16)pa3;
        pfa[4]=(_Float16)pa4; pfa[5]=(_Float16)pa5; pfa[6]=(_Float16)pa6; pfa[7]=(_Float16)pa7;
        pfb[0]=(_Float16)pb0; pfb[1]=(_Float16)pb1; pfb[2]=(_Float16)pb2; pfb[3]=(_Float16)pb3;
        pfb[4]=(_Float16)pb4; pfb[5]=(_Float16)pb5; pfb[6]=(_Float16)pb6; pfb[7]=(_Float16)pb7;
        // ---- PV: V fragments shared between both sub-tiles; no rescale ----
#pragma unroll
        for (int hc = 0; hc < 8; ++hc) {
            oa[hc] = __builtin_amdgcn_mfma_f32_16x16x32_f16(vf[hc], pfa, oa[hc], 0, 0, 0);
            ob[hc] = __builtin_amdgcn_mfma_f32_16x16x32_f16(vf[hc], pfb, ob[hc], 0, 0, 0);
        }
        // ---- rotate K buffers ----
#pragma unroll
        for (int kk = 0; kk < 4; ++kk) { kc0[kk] = kn0[kk]; kc1[kk] = kn1[kk]; }
    }

    // ---- single deferred l-reduction ----
    la += __shfl_xor(la, 16); la += __shfl_xor(la, 32);
    lb += __shfl_xor(lb, 16); lb += __shfl_xor(lb, 32);

    // ---- merge the 8 KV-split partials (straight sums) ----
    sm_l[wid][lo]      = la;
    sm_l[wid][16 + lo] = lb;
#pragma unroll
    for (int hc = 0; hc < 8; ++hc) {
        half4v va, vb;
#pragma unroll
        for (int j = 0; j < 4; ++j) { va[j] = (_Float16)oa[hc][j]; vb[j] = (_Float16)ob[hc][j]; }
        *(half4v*)(&sm_o[wid][lo][hc * 16 + 4 * hi])      = va;
        *(half4v*)(&sm_o[wid][16 + lo][hc * 16 + 4 * hi]) = vb;
    }
    __syncthreads();

#pragma unroll
    for (int qh = 0; qh < 2; ++qh) {
        const int q = qh * 16 + lo;
        float L = 0.f;
#pragma unroll
        for (int w = 0; w < 8; ++w) L += sm_l[w][q];
        const float invL = 1.f / L;
        float4v ov = {0.f, 0.f, 0.f, 0.f};
#pragma unroll
        for (int w = 0; w < 8; ++w) {
            half4v tv = *(const half4v*)(&sm_o[w][q][wid * 16 + 4 * hi]);
#pragma unroll
            for (int j = 0; j < 4; ++j) ov[j] += (float)tv[j];
        }
#pragma unroll
        for (int j = 0; j < 4; ++j) ov[j] *= invL;
        *(float4v*)(Out + ((size_t)b * S_ + q0 + q) * H_ + wid * 16 + 4 * hi) = ov;
    }
}

extern "C" void kernel_launch(void* const* d_in, const int* in_sizes, int n_in,
                              void* d_out, int out_size, void* d_ws, size_t ws_size,
                              hipStream_t stream) {
    const float* x  = (const float*)d_in[0];
    const float* Wq = (const float*)d_in[1];
    const float* bq = (const float*)d_in[2];
    const float* Wk = (const float*)d_in[3];
    const float* bk = (const float*)d_in[4];
    const float* Wv = (const float*)d_in[5];
    const float* bv = (const float*)d_in[6];
    float* out = (float*)d_out;   // reference output dtype = float32

    char* ws = (char*)d_ws;
    _Float16* WT = (_Float16*)ws;                       //   786,432 B
    _Float16* Qf = (_Float16*)(ws + 786432);            // 4,194,304 B
    _Float16* Kz = (_Float16*)(ws + 786432 + 4194304);  // 4 MB fragment-major
    _Float16* Vz = (_Float16*)(ws + 786432 + 8388608);  // 4 MB fragment-major

    hipLaunchKernelGGL(k_cvt_w, dim3(512, 3), dim3(256), 0, stream, Wq, Wk, Wv, WT);
    hipLaunchKernelGGL(k_proj, dim3(768), dim3(256), 0, stream,
                       x, WT, bq, bk, bv, Qf, Kz, Vz);
    hipLaunchKernelGGL(k_attn, dim3(512), dim3(512), 0, stream, Qf, Kz, Vz, out);
}